// Round 4
// baseline (10791.100 us; speedup 1.0000x reference)
//
#include <hip/hip_runtime.h>
#include <hip/hip_bf16.h>

#define NN 2048
#define HH 1024
#define MM 4096          // 4*H
#define NWG 128
#define TPB 256

__device__ __forceinline__ float sigmoidf_(float x) {
    return 1.0f / (1.0f + __expf(-x));
}
// fp32 -> bf16 bits (RNE), finite inputs
__device__ __forceinline__ unsigned f2bf_bits(float f) {
    unsigned u = __float_as_uint(f);
    u += 0x7fffu + ((u >> 16) & 1u);
    return u >> 16;
}
__device__ __forceinline__ float bf_bits2f(unsigned s) {
    return __uint_as_float(s << 16);
}

// ---------------------------------------------------------------- init flags
__global__ void init_flags(int* flags) {
    if (threadIdx.x < NWG) flags[threadIdx.x] = -1;
}

// ---------------------------------------------------------------- gx GEMM
// gx[n][m] = sum_d emb[inputs[n]][d] * Wx[m][d] + bx[m]   (m = g*1024+h)
// Stored as bf16 bits (16 MB workspace); error ~1e-4 << 3.8e-3 threshold.
__global__ void __launch_bounds__(256) gx_gemm(
    const int* __restrict__ idx, const float* __restrict__ emb,
    const float* __restrict__ Wx, const float* __restrict__ bx,
    unsigned short* __restrict__ gx)
{
    __shared__ float As[16][64];
    __shared__ float Bs[16][64];
    const int tid = threadIdx.x;
    const int tx = tid & 15, ty = tid >> 4;
    const int mt = blockIdx.x, nt = blockIdx.y;
    const int lrow = tid >> 2;            // 0..63
    const int lk   = (tid & 3) << 2;      // 0,4,8,12
    const int gn = nt * 64 + lrow;
    const int gm = mt * 64 + lrow;
    const float* arow = emb + (size_t)idx[gn] * HH;
    const float* wrow = Wx + (size_t)gm * HH;
    float acc[4][4] = {};
    for (int k0 = 0; k0 < HH; k0 += 16) {
        float4 av = *(const float4*)(arow + k0 + lk);
        float4 wv = *(const float4*)(wrow + k0 + lk);
        __syncthreads();
        As[lk + 0][lrow] = av.x; As[lk + 1][lrow] = av.y;
        As[lk + 2][lrow] = av.z; As[lk + 3][lrow] = av.w;
        Bs[lk + 0][lrow] = wv.x; Bs[lk + 1][lrow] = wv.y;
        Bs[lk + 2][lrow] = wv.z; Bs[lk + 3][lrow] = wv.w;
        __syncthreads();
        #pragma unroll
        for (int k = 0; k < 16; ++k) {
            const float4 a = *(const float4*)&As[k][ty * 4];
            const float4 b = *(const float4*)&Bs[k][tx * 4];
            const float aa[4] = {a.x, a.y, a.z, a.w};
            const float bb[4] = {b.x, b.y, b.z, b.w};
            #pragma unroll
            for (int i = 0; i < 4; ++i)
                #pragma unroll
                for (int j = 0; j < 4; ++j)
                    acc[i][j] += aa[i] * bb[j];
        }
    }
    #pragma unroll
    for (int i = 0; i < 4; ++i) {
        const int gr = nt * 64 + ty * 4 + i;
        #pragma unroll
        for (int j = 0; j < 4; ++j) {
            const int gc = mt * 64 + tx * 4 + j;
            gx[(size_t)gr * MM + gc] = (unsigned short)f2bf_bits(acc[i][j] + bx[gc]);
        }
    }
}

// ---------------------------------------------------------------- tree scan
// 128 WGs, all resident (plain launch, 128 <= 256 CUs). WG b owns hidden
// elements [8b, 8b+8); Wh rows live in registers. One flag publish per node.
// f-gate of child j is deferred to round t=parent[j] (child h re-read anyway),
// c_j kept in a 16-deep LDS ring (parent[j]-j <= 8). h history = d_out (fp32).
__global__ void __launch_bounds__(TPB, 1) lstm_scan(
    const int* __restrict__ parent_g,
    const float* __restrict__ Wh,
    const float* __restrict__ bh,
    const unsigned short* __restrict__ gx,   // bf16 bits [N][4][H]
    int* flags,
    float* out)   // fp32: [ hs (NN*HH) | c_root (HH) | h_root (HH) ]
{
    const int b      = blockIdx.x;
    const int tid    = threadIdx.x;
    const int e_loc  = tid >> 5;       // 0..7
    const int lane32 = tid & 31;
    const int e_glob = b * 8 + e_loc;

    __shared__ int   par[NN];          // 8 KB
    __shared__ float hj[HH];           // 4 KB child-row staging
    __shared__ float c_ring[16][8];
    __shared__ float fc_buf[8];
    __shared__ float gx_buf[4][8];

    for (int i = tid; i < NN; i += TPB) par[i] = parent_g[i];

    float w_i[32], w_o[32], w_u[32], w_f[32];
    {
        const float* wi = Wh + ((size_t)(0 * HH + e_glob)) * HH + lane32;
        const float* wo = Wh + ((size_t)(1 * HH + e_glob)) * HH + lane32;
        const float* wu = Wh + ((size_t)(2 * HH + e_glob)) * HH + lane32;
        const float* wf = Wh + ((size_t)(3 * HH + e_glob)) * HH + lane32;
        #pragma unroll
        for (int s = 0; s < 32; ++s) {
            w_i[s] = wi[s * 32];
            w_o[s] = wo[s * 32];
            w_u[s] = wu[s * 32];
            w_f[s] = wf[s * 32];
        }
    }
    const float bhi = bh[0 * HH + e_glob];
    const float bho = bh[1 * HH + e_glob];
    const float bhu = bh[2 * HH + e_glob];
    const float bhf = bh[3 * HH + e_glob];
    __syncthreads();

    int seen = -1;   // cached monotone lower bound of flags[tid] (tid < NWG)

    for (int t = 0; t < NN; ++t) {
        const int lo = (t >= 8) ? t - 8 : 0;
        int maxc = -1;
        for (int j = lo; j < t; ++j)
            if (par[j] == t) maxc = j;          // uniform across threads

        if (maxc >= 0 && tid < NWG && seen < maxc) {
            int v;
            while ((v = __hip_atomic_load(&flags[tid], __ATOMIC_ACQUIRE,
                                          __HIP_MEMORY_SCOPE_AGENT)) < maxc)
                __builtin_amdgcn_s_sleep(1);
            seen = v;
        }
        __syncthreads();

        if (tid < 32) {
            const int g = tid >> 3, e = tid & 7;
            gx_buf[g][e] = bf_bits2f(gx[(size_t)t * MM + g * HH + b * 8 + e]);
        }
        if (tid < 8) fc_buf[tid] = 0.0f;
        __syncthreads();

        float hsum[32];
        #pragma unroll
        for (int s = 0; s < 32; ++s) hsum[s] = 0.0f;

        // children: accumulate hsum and f_j * c_j
        for (int j = lo; j < t; ++j) {
            if (par[j] != t) continue;
            {
                const float* src = out + (size_t)j * HH;
                #pragma unroll
                for (int q = 0; q < 4; ++q) {
                    const int k = tid + q * TPB;
                    hj[k] = __hip_atomic_load(src + k, __ATOMIC_RELAXED,
                                              __HIP_MEMORY_SCOPE_AGENT);
                }
            }
            __syncthreads();
            float fdot = 0.0f;
            #pragma unroll
            for (int s = 0; s < 32; ++s) {
                const float hv = hj[lane32 + 32 * s];
                hsum[s] += hv;
                fdot += w_f[s] * hv;
            }
            #pragma unroll
            for (int off = 16; off > 0; off >>= 1)
                fdot += __shfl_down(fdot, off, 32);
            if (lane32 == 0) {
                const float f = sigmoidf_(gx_buf[3][e_loc] + fdot + bhf);
                fc_buf[e_loc] += f * c_ring[j & 15][e_loc];
            }
            __syncthreads();
        }

        // gate dots on hsum (registers only)
        float di = 0.0f, dv = 0.0f, du = 0.0f;
        #pragma unroll
        for (int s = 0; s < 32; ++s) {
            const float hv = hsum[s];
            di += w_i[s] * hv;
            dv += w_o[s] * hv;
            du += w_u[s] * hv;
        }
        #pragma unroll
        for (int off = 16; off > 0; off >>= 1) {
            di += __shfl_down(di, off, 32);
            dv += __shfl_down(dv, off, 32);
            du += __shfl_down(du, off, 32);
        }
        if (lane32 == 0) {
            const float iv = sigmoidf_(gx_buf[0][e_loc] + di + bhi);
            const float ov = sigmoidf_(gx_buf[1][e_loc] + dv + bho);
            const float uv = tanhf(gx_buf[2][e_loc] + du + bhu);
            const float c  = iv * uv + fc_buf[e_loc];
            const float h  = ov * tanhf(c);
            c_ring[t & 15][e_loc] = c;
            __hip_atomic_store(out + (size_t)t * HH + e_glob, h,
                               __ATOMIC_RELAXED, __HIP_MEMORY_SCOPE_AGENT);
            if (t == NN - 1) {
                __hip_atomic_store(out + (size_t)NN * HH + e_glob, c,
                                   __ATOMIC_RELAXED, __HIP_MEMORY_SCOPE_AGENT);
                __hip_atomic_store(out + (size_t)NN * HH + HH + e_glob, h,
                                   __ATOMIC_RELAXED, __HIP_MEMORY_SCOPE_AGENT);
            }
        }
        __syncthreads();   // barrier drains vmcnt -> h stores globally visible
        if (tid == 0)
            __hip_atomic_store(&flags[b], t, __ATOMIC_RELEASE,
                               __HIP_MEMORY_SCOPE_AGENT);
    }
}

// ---------------------------------------------------------------- launch
extern "C" void kernel_launch(void* const* d_in, const int* in_sizes, int n_in,
                              void* d_out, int out_size, void* d_ws, size_t ws_size,
                              hipStream_t stream)
{
    const int*   inputs = (const int*)d_in[0];
    const int*   parent = (const int*)d_in[1];
    const float* emb    = (const float*)d_in[2];
    const float* Wx     = (const float*)d_in[3];
    const float* bx     = (const float*)d_in[4];
    const float* Wh     = (const float*)d_in[5];
    const float* bh     = (const float*)d_in[6];
    float* out = (float*)d_out;          // fp32 output (reference is fp32)

    char* ws = (char*)d_ws;
    int*  flags = (int*)ws;                               // 512 B
    unsigned short* gx = (unsigned short*)(ws + 1024);    // 16 MB bf16 bits

    hipLaunchKernelGGL(init_flags, dim3(1), dim3(128), 0, stream, flags);
    hipLaunchKernelGGL(gx_gemm, dim3(MM / 64, NN / 64), dim3(256), 0, stream,
                       inputs, emb, Wx, bx, gx);
    hipLaunchKernelGGL(lstm_scan, dim3(NWG), dim3(TPB), 0, stream,
                       parent, Wh, bh, gx, flags, out);
}